// Round 5
// baseline (233.123 us; speedup 1.0000x reference)
//
#include <hip/hip_runtime.h>
#include <hip/hip_fp16.h>
#include <cstdint>
#include <cstddef>

#define NHEAD 16
#define HDIM  64
#define HID   1024

using f16x8  = __attribute__((ext_vector_type(8))) _Float16;
using f32x4  = __attribute__((ext_vector_type(4))) float;
using f32x16 = __attribute__((ext_vector_type(16))) float;

typedef const __attribute__((address_space(1))) unsigned int* gq_t;
typedef __attribute__((address_space(3))) unsigned int* lq_t;

// ------------------------------------------------------- fused converter
__global__ void cvt_all(const float* __restrict__ x,
                        const float* __restrict__ Wq, const float* __restrict__ Wk,
                        const float* __restrict__ Wv, const float* __restrict__ Wo,
                        const float* __restrict__ bq, const float* __restrict__ bk,
                        const float* __restrict__ bv,
                        _Float16* __restrict__ x16, _Float16* __restrict__ wqkv,
                        _Float16* __restrict__ wo, float* __restrict__ bqkv,
                        int n8x, int n8w)
{
    const int n8tot = n8x + 4 * n8w;
    for (int i = blockIdx.x * blockDim.x + threadIdx.x; i < n8tot; i += gridDim.x * blockDim.x) {
        const float* src;
        _Float16* dst;
        size_t off;
        if (i < n8x) {
            src = x; dst = x16; off = (size_t)i;
        } else {
            const int j = i - n8x;
            const int seg = j / n8w;
            off = (size_t)(j - seg * n8w);
            src = (seg == 0) ? Wq : (seg == 1) ? Wk : (seg == 2) ? Wv : Wo;
            dst = (seg < 3) ? (wqkv + (size_t)seg * HID * HID) : wo;
        }
        const float4* p = (const float4*)(src + off * 8);
        float4 a = p[0], b = p[1];
        f16x8 o;
        o[0] = (_Float16)a.x; o[1] = (_Float16)a.y; o[2] = (_Float16)a.z; o[3] = (_Float16)a.w;
        o[4] = (_Float16)b.x; o[5] = (_Float16)b.y; o[6] = (_Float16)b.z; o[7] = (_Float16)b.w;
        *(f16x8*)(dst + off * 8) = o;
    }
    const int bi = blockIdx.x * blockDim.x + threadIdx.x;
    if (bi < 384) {
        const int seg = bi >> 7;
        const int off = (bi & 127) * 8;
        const float* src = (seg == 0) ? bq : (seg == 1) ? bk : bv;
        const float4* p = (const float4*)(src + off);
        float4 a = p[0], b = p[1];
        float4* q = (float4*)(bqkv + seg * HID + off);
        q[0] = a; q[1] = b;
    }
}

// ------------------------------------------------------------------- GEMM
// C[M][N] = A[M][K] @ B[N][K]^T + bias[N]
// 128x128 tile, 4 waves (2x2), BK=64, global_load_lds staging,
// XOR slot-swizzle (slot ^= row&7). MFMA 32x32x16 f16 (per wave: 2x2
// 32x32 tiles, 16 MFMA + 16 ds_read_b128 per K-tile — half the MFMA
// instruction count of the 16x16x32 version at ~14% higher pipe rate).
template <typename OutT>
__global__ __launch_bounds__(256, 4)
void gemm_bt(const _Float16* __restrict__ A, const _Float16* __restrict__ Bw,
             const float* __restrict__ bias, OutT* __restrict__ C,
             int M, int N, int K)
{
    __shared__ _Float16 As[128 * 64];
    __shared__ _Float16 Bs[128 * 64];

    const int tid  = threadIdx.x;
    const int lane = tid & 63;
    const int wid  = tid >> 6;
    const int wm   = wid >> 1;   // 0..1
    const int wn   = wid & 1;    // 0..1
    const int m0   = blockIdx.y * 128;
    const int n0   = blockIdx.x * 128;

    f32x16 acc[2][2] = {};

    const int r_in  = lane >> 3;       // 0..7 row within wave's 8-row strip
    const int s_lds = lane & 7;        // 0..7 16B slot within row
    const int l31   = lane & 31;
    const int kh    = lane >> 5;       // k-half 0..1

    for (int k0 = 0; k0 < K; k0 += 64) {
        // ---- stage A,B tiles (128 rows x 64 f16 = 16 KiB each)
        #pragma unroll
        for (int j = 0; j < 4; ++j) {
            const int rbase = j * 32 + wid * 8;       // wave-uniform
            const int r     = rbase + r_in;
            const int s_g   = s_lds ^ (r & 7);        // pre-swizzled global source
            const _Float16* ga = A  + (size_t)(m0 + r) * K + k0 + s_g * 8;
            const _Float16* gb = Bw + (size_t)(n0 + r) * K + k0 + s_g * 8;
            __builtin_amdgcn_global_load_lds((gq_t)(const void*)ga,
                                             (lq_t)(void*)(As + rbase * 64), 16, 0, 0);
            __builtin_amdgcn_global_load_lds((gq_t)(const void*)gb,
                                             (lq_t)(void*)(Bs + rbase * 64), 16, 0, 0);
        }
        __syncthreads();

        // ---- compute: 4 K-steps of 16; 4 MFMA (32x32x16) each
        #pragma unroll
        for (int ks = 0; ks < 4; ++ks) {
            f16x8 af[2], bf[2];
            #pragma unroll
            for (int mt = 0; mt < 2; ++mt) {
                const int row  = wm * 64 + mt * 32 + l31;
                const int slot = (ks * 2 + kh) ^ (row & 7);
                af[mt] = *(const f16x8*)&As[row * 64 + slot * 8];
            }
            #pragma unroll
            for (int nt = 0; nt < 2; ++nt) {
                const int row  = wn * 64 + nt * 32 + l31;
                const int slot = (ks * 2 + kh) ^ (row & 7);
                bf[nt] = *(const f16x8*)&Bs[row * 64 + slot * 8];
            }
            #pragma unroll
            for (int mt = 0; mt < 2; ++mt)
                #pragma unroll
                for (int nt = 0; nt < 2; ++nt)
                    acc[mt][nt] = __builtin_amdgcn_mfma_f32_32x32x16_f16(
                        af[mt], bf[nt], acc[mt][nt], 0, 0, 0);
        }
        __syncthreads();
    }

    // ---- epilogue: bias + store.
    // D layout (32x32): col = lane&31, row = (reg&3) + 8*(reg>>2) + 4*(lane>>5)
    #pragma unroll
    for (int nt = 0; nt < 2; ++nt) {
        const int col = n0 + wn * 64 + nt * 32 + l31;
        const float bv = bias[col];
        #pragma unroll
        for (int mt = 0; mt < 2; ++mt) {
            const int rowbase = m0 + wm * 64 + mt * 32 + 4 * kh;
            #pragma unroll
            for (int r = 0; r < 16; ++r) {
                const int row = rowbase + (r & 3) + 8 * (r >> 2);
                C[(size_t)row * N + col] = (OutT)(acc[mt][nt][r] + bv);
            }
        }
    }
}

// --------------------------------------------------------------- attention
__global__ __launch_bounds__(128, 2)
void attn_kernel(const _Float16* __restrict__ qkv, const float* __restrict__ scale,
                 _Float16* __restrict__ out)
{
    __shared__ _Float16 kv[8][2048];   // per token: k[0..1024), v[1024..2048)
    __shared__ float sc[64];

    const int tid  = threadIdx.x;
    const int tok0 = blockIdx.x * 8;

    if (tid < 64) sc[tid] = scale[tid];

    #pragma unroll
    for (int it = 0; it < 16; ++it) {
        const int vid = tid + it * 128;
        const int tok = vid >> 8;
        const int ofs = (vid & 255) * 8;
        *(f16x8*)&kv[tok][ofs] =
            *(const f16x8*)&qkv[(size_t)(tok0 + tok) * 3072 + 1024 + ofs];
    }
    __syncthreads();

    const int tok = tid >> 4;
    const int h   = tid & 15;
    const size_t qbase = (size_t)(tok0 + tok) * 3072 + h * 64;

    float q[64];
    #pragma unroll
    for (int d0 = 0; d0 < 64; d0 += 8) {
        f16x8 qv = *(const f16x8*)&qkv[qbase + d0];
        #pragma unroll
        for (int j = 0; j < 8; ++j) q[d0 + j] = (float)qv[j] * sc[d0 + j];
    }

    float s[16];
    #pragma unroll
    for (int t = 0; t < 16; ++t) {
        float a = 0.f;
        #pragma unroll
        for (int d0 = 0; d0 < 64; d0 += 8) {
            f16x8 kvv = *(const f16x8*)&kv[tok][t * 64 + d0];
            #pragma unroll
            for (int j = 0; j < 8; ++j) a += q[d0 + j] * (float)kvv[j];
        }
        s[t] = a * 0.125f;
    }

    float mx = s[0];
    #pragma unroll
    for (int t = 1; t < 16; ++t) mx = fmaxf(mx, s[t]);
    float sum = 0.f;
    #pragma unroll
    for (int t = 0; t < 16; ++t) { s[t] = __expf(s[t] - mx); sum += s[t]; }
    const float inv = 1.f / sum;

    float o[64] = {};
    #pragma unroll
    for (int t = 0; t < 16; ++t) {
        const float a = s[t] * inv;
        #pragma unroll
        for (int d0 = 0; d0 < 64; d0 += 8) {
            f16x8 vv = *(const f16x8*)&kv[tok][1024 + t * 64 + d0];
            #pragma unroll
            for (int j = 0; j < 8; ++j) o[d0 + j] += a * (float)vv[j];
        }
    }

    #pragma unroll
    for (int d0 = 0; d0 < 64; d0 += 8) {
        f16x8 ov;
        #pragma unroll
        for (int j = 0; j < 8; ++j) ov[j] = (_Float16)o[d0 + j];
        *(f16x8*)&out[(size_t)(tok0 + tok) * 1024 + h * 64 + d0] = ov;
    }
}

// ----------------------------------------------------------------- launcher
extern "C" void kernel_launch(void* const* d_in, const int* in_sizes, int n_in,
                              void* d_out, int out_size, void* d_ws, size_t ws_size,
                              hipStream_t stream)
{
    const float* x     = (const float*)d_in[0];
    const float* Wq    = (const float*)d_in[1];
    const float* bq    = (const float*)d_in[2];
    const float* Wk    = (const float*)d_in[3];
    const float* bk    = (const float*)d_in[4];
    const float* Wv    = (const float*)d_in[5];
    const float* bv    = (const float*)d_in[6];
    const float* Wo    = (const float*)d_in[7];
    const float* bo    = (const float*)d_in[8];
    const float* scale = (const float*)d_in[9];
    float* out = (float*)d_out;

    const int M = in_sizes[0] / HID;   // 16384 tokens

    char* ws = (char*)d_ws;
    _Float16* x16    = (_Float16*)ws;
    _Float16* attn16 = x16;
    _Float16* wqkv16 = (_Float16*)(ws + (size_t)M * HID * 2);
    _Float16* wo16   = wqkv16 + (size_t)3 * HID * HID;
    float*    bqkv   = (float*)(wo16 + (size_t)HID * HID);
    _Float16* qkv16  = (_Float16*)((char*)bqkv + 3 * HID * 4);

    cvt_all<<<4096, 256, 0, stream>>>(x, Wq, Wk, Wv, Wo, bq, bk, bv,
                                      x16, wqkv16, wo16, bqkv,
                                      M * HID / 8, HID * HID / 8);

    // QKV GEMM: [M,1024] @ [3072,1024]^T -> qkv16 [M,3072] (f16)
    gemm_bt<_Float16><<<dim3(3 * HID / 128, M / 128), 256, 0, stream>>>(
        x16, wqkv16, bqkv, qkv16, M, 3 * HID, HID);

    // per-token head-mix attention -> attn16 [M,1024] (f16)
    attn_kernel<<<M / 8, 128, 0, stream>>>(qkv16, scale, attn16);

    // output GEMM: [M,1024] @ [1024,1024]^T + bo -> out (f32)
    gemm_bt<float><<<dim3(HID / 128, M / 128), 256, 0, stream>>>(
        attn16, wo16, bo, out, M, HID, HID);
}

// Round 6
// 216.482 us; speedup vs baseline: 1.0769x; 1.0769x over previous
//
#include <hip/hip_runtime.h>
#include <hip/hip_fp16.h>
#include <cstdint>
#include <cstddef>

#define NHEAD 16
#define HDIM  64
#define HID   1024

using f16x8 = __attribute__((ext_vector_type(8))) _Float16;
using f16x2 = __attribute__((ext_vector_type(2))) _Float16;
using f32x4 = __attribute__((ext_vector_type(4))) float;

typedef const __attribute__((address_space(1))) unsigned int* gq_t;
typedef __attribute__((address_space(3))) unsigned int* lq_t;

// ------------------------------------------------------- fused converter
__global__ void cvt_all(const float* __restrict__ x,
                        const float* __restrict__ Wq, const float* __restrict__ Wk,
                        const float* __restrict__ Wv, const float* __restrict__ Wo,
                        const float* __restrict__ bq, const float* __restrict__ bk,
                        const float* __restrict__ bv,
                        _Float16* __restrict__ x16, _Float16* __restrict__ wqkv,
                        _Float16* __restrict__ wo, float* __restrict__ bqkv,
                        int n8x, int n8w)
{
    const int n8tot = n8x + 4 * n8w;
    for (int i = blockIdx.x * blockDim.x + threadIdx.x; i < n8tot; i += gridDim.x * blockDim.x) {
        const float* src;
        _Float16* dst;
        size_t off;
        if (i < n8x) {
            src = x; dst = x16; off = (size_t)i;
        } else {
            const int j = i - n8x;
            const int seg = j / n8w;
            off = (size_t)(j - seg * n8w);
            src = (seg == 0) ? Wq : (seg == 1) ? Wk : (seg == 2) ? Wv : Wo;
            dst = (seg < 3) ? (wqkv + (size_t)seg * HID * HID) : wo;
        }
        const float4* p = (const float4*)(src + off * 8);
        float4 a = p[0], b = p[1];
        f16x8 o;
        o[0] = (_Float16)a.x; o[1] = (_Float16)a.y; o[2] = (_Float16)a.z; o[3] = (_Float16)a.w;
        o[4] = (_Float16)b.x; o[5] = (_Float16)b.y; o[6] = (_Float16)b.z; o[7] = (_Float16)b.w;
        *(f16x8*)(dst + off * 8) = o;
    }
    const int bi = blockIdx.x * blockDim.x + threadIdx.x;
    if (bi < 384) {
        const int seg = bi >> 7;
        const int off = (bi & 127) * 8;
        const float* src = (seg == 0) ? bq : (seg == 1) ? bk : bv;
        const float4* p = (const float4*)(src + off);
        float4 a = p[0], b = p[1];
        float4* q = (float4*)(bqkv + seg * HID + off);
        q[0] = a; q[1] = b;
    }
}

// ------------------------------------------------------------------- GEMM
// C[M][N] = A[M][K] @ B[N][K]^T + bias[N]
// 128x128 tile, 4 waves (2x2), BK=64, global_load_lds staging,
// XOR slot-swizzle (slot ^= row&7) -> measured 0 bank conflicts.
// (R4-proven: 110.5 us QKV / 37 us out at 932 TF; 16x16x32 MFMA.
//  32x32x16 variant measured WORSE: 129 us + 1.26e7 conflicts — do not use.)
template <typename OutT>
__global__ __launch_bounds__(256, 4)
void gemm_bt(const _Float16* __restrict__ A, const _Float16* __restrict__ Bw,
             const float* __restrict__ bias, OutT* __restrict__ C,
             int M, int N, int K)
{
    __shared__ _Float16 As[128 * 64];
    __shared__ _Float16 Bs[128 * 64];

    const int tid  = threadIdx.x;
    const int lane = tid & 63;
    const int wid  = tid >> 6;
    const int wm   = wid >> 1;   // 0..1
    const int wn   = wid & 1;    // 0..1
    const int m0   = blockIdx.y * 128;
    const int n0   = blockIdx.x * 128;

    f32x4 acc[4][4] = {};

    const int r_in  = lane >> 3;       // 0..7 row within wave's 8-row strip
    const int s_lds = lane & 7;        // 0..7 16B slot within row

    for (int k0 = 0; k0 < K; k0 += 64) {
        #pragma unroll
        for (int j = 0; j < 4; ++j) {
            const int rbase = j * 32 + wid * 8;       // wave-uniform
            const int r     = rbase + r_in;
            const int s_g   = s_lds ^ (r & 7);        // pre-swizzled global source
            const _Float16* ga = A  + (size_t)(m0 + r) * K + k0 + s_g * 8;
            const _Float16* gb = Bw + (size_t)(n0 + r) * K + k0 + s_g * 8;
            __builtin_amdgcn_global_load_lds((gq_t)(const void*)ga,
                                             (lq_t)(void*)(As + rbase * 64), 16, 0, 0);
            __builtin_amdgcn_global_load_lds((gq_t)(const void*)gb,
                                             (lq_t)(void*)(Bs + rbase * 64), 16, 0, 0);
        }
        __syncthreads();

        const int g = lane >> 4;              // k-group 0..3
        #pragma unroll
        for (int kk = 0; kk < 2; ++kk) {
            f16x8 af[4], bf[4];
            #pragma unroll
            for (int mi = 0; mi < 4; ++mi) {
                const int row  = wm * 64 + mi * 16 + (lane & 15);
                const int slot = (kk * 4 + g) ^ (row & 7);
                af[mi] = *(const f16x8*)&As[row * 64 + slot * 8];
            }
            #pragma unroll
            for (int ni = 0; ni < 4; ++ni) {
                const int row  = wn * 64 + ni * 16 + (lane & 15);
                const int slot = (kk * 4 + g) ^ (row & 7);
                bf[ni] = *(const f16x8*)&Bs[row * 64 + slot * 8];
            }
            #pragma unroll
            for (int mi = 0; mi < 4; ++mi)
                #pragma unroll
                for (int ni = 0; ni < 4; ++ni)
                    acc[mi][ni] = __builtin_amdgcn_mfma_f32_16x16x32_f16(
                        af[mi], bf[ni], acc[mi][ni], 0, 0, 0);
        }
        __syncthreads();
    }

    #pragma unroll
    for (int ni = 0; ni < 4; ++ni) {
        const int col = n0 + wn * 64 + ni * 16 + (lane & 15);
        const float bv = bias[col];
        #pragma unroll
        for (int mi = 0; mi < 4; ++mi) {
            const int rowb = m0 + wm * 64 + mi * 16 + (lane >> 4) * 4;
            #pragma unroll
            for (int q = 0; q < 4; ++q) {
                const float val = acc[mi][ni][q] + bv;
                C[(size_t)(rowb + q) * N + col] = (OutT)val;
            }
        }
    }
}

// --------------------------------------------------------------- attention
// Per token: q,k,v in [16][64]; scores = (q*scale)@k^T / 8; softmax over t;
// out = attn @ v.  8 tokens/block, 128 threads: thread = (token, head-row h).
// Packed math: scores via fdot2 (f32 accum), PV via pk_fma_f16 (f16 accum).
__global__ __launch_bounds__(128, 2)
void attn_kernel(const _Float16* __restrict__ qkv, const float* __restrict__ scale,
                 _Float16* __restrict__ out)
{
    __shared__ _Float16 kv[8][2048];   // per token: k[0..1024), v[1024..2048)
    __shared__ _Float16 sc2[64];       // scale * 0.125 in f16

    const int tid  = threadIdx.x;
    const int tok0 = blockIdx.x * 8;

    if (tid < 64) sc2[tid] = (_Float16)(scale[tid] * 0.125f);

    #pragma unroll
    for (int it = 0; it < 16; ++it) {
        const int vid = tid + it * 128;
        const int tok = vid >> 8;
        const int ofs = (vid & 255) * 8;
        *(f16x8*)&kv[tok][ofs] =
            *(const f16x8*)&qkv[(size_t)(tok0 + tok) * 3072 + 1024 + ofs];
    }
    __syncthreads();

    const int tok = tid >> 4;
    const int h   = tid & 15;
    const size_t qbase = (size_t)(tok0 + tok) * 3072 + h * 64;

    // q * scale * 0.125, kept as 32 f16 pairs
    f16x2 q2[32];
    #pragma unroll
    for (int d0 = 0; d0 < 8; ++d0) {
        f16x8 qv = *(const f16x8*)&qkv[qbase + d0 * 8];
        f16x8 sv = *(const f16x8*)&sc2[d0 * 8];
        #pragma unroll
        for (int j = 0; j < 4; ++j) {
            f16x2 t;
            t[0] = qv[2 * j]     * sv[2 * j];
            t[1] = qv[2 * j + 1] * sv[2 * j + 1];
            q2[d0 * 4 + j] = t;
        }
    }

    // scores: fdot2 (2 f16 MACs/instr, f32 accumulator)
    float s[16];
    #pragma unroll
    for (int t = 0; t < 16; ++t) {
        float a = 0.f;
        #pragma unroll
        for (int p = 0; p < 32; ++p) {
            f16x2 kp = *(const f16x2*)&kv[tok][t * 64 + p * 2];
            a = __builtin_amdgcn_fdot2(q2[p], kp, a, false);
        }
        s[t] = a;
    }

    float mx = s[0];
    #pragma unroll
    for (int t = 1; t < 16; ++t) mx = fmaxf(mx, s[t]);
    float sum = 0.f;
    #pragma unroll
    for (int t = 0; t < 16; ++t) { s[t] = __expf(s[t] - mx); sum += s[t]; }
    const float inv = 1.f / sum;

    // PV: packed f16 fma (attn weights in [0,1], sum 1 -> f16 accum safe)
    f16x2 o2[32] = {};
    #pragma unroll
    for (int t = 0; t < 16; ++t) {
        const _Float16 aw = (_Float16)(s[t] * inv);
        f16x2 aw2; aw2[0] = aw; aw2[1] = aw;
        #pragma unroll
        for (int p = 0; p < 32; ++p) {
            f16x2 vp = *(const f16x2*)&kv[tok][1024 + t * 64 + p * 2];
            o2[p] += aw2 * vp;     // v_pk_fma_f16
        }
    }

    #pragma unroll
    for (int d0 = 0; d0 < 8; ++d0) {
        f16x8 ov;
        #pragma unroll
        for (int j = 0; j < 4; ++j) { ov[2*j] = o2[d0*4+j][0]; ov[2*j+1] = o2[d0*4+j][1]; }
        *(f16x8*)&out[(size_t)(tok0 + tok) * 1024 + h * 64 + d0 * 8] = ov;
    }
}

// ----------------------------------------------------------------- launcher
extern "C" void kernel_launch(void* const* d_in, const int* in_sizes, int n_in,
                              void* d_out, int out_size, void* d_ws, size_t ws_size,
                              hipStream_t stream)
{
    const float* x     = (const float*)d_in[0];
    const float* Wq    = (const float*)d_in[1];
    const float* bq    = (const float*)d_in[2];
    const float* Wk    = (const float*)d_in[3];
    const float* bk    = (const float*)d_in[4];
    const float* Wv    = (const float*)d_in[5];
    const float* bv    = (const float*)d_in[6];
    const float* Wo    = (const float*)d_in[7];
    const float* bo    = (const float*)d_in[8];
    const float* scale = (const float*)d_in[9];
    float* out = (float*)d_out;

    const int M = in_sizes[0] / HID;   // 16384 tokens

    char* ws = (char*)d_ws;
    _Float16* x16    = (_Float16*)ws;
    _Float16* attn16 = x16;
    _Float16* wqkv16 = (_Float16*)(ws + (size_t)M * HID * 2);
    _Float16* wo16   = wqkv16 + (size_t)3 * HID * HID;
    float*    bqkv   = (float*)(wo16 + (size_t)HID * HID);
    _Float16* qkv16  = (_Float16*)((char*)bqkv + 3 * HID * 4);

    cvt_all<<<4096, 256, 0, stream>>>(x, Wq, Wk, Wv, Wo, bq, bk, bv,
                                      x16, wqkv16, wo16, bqkv,
                                      M * HID / 8, HID * HID / 8);

    // QKV GEMM: [M,1024] @ [3072,1024]^T -> qkv16 [M,3072] (f16)
    gemm_bt<_Float16><<<dim3(3 * HID / 128, M / 128), 256, 0, stream>>>(
        x16, wqkv16, bqkv, qkv16, M, 3 * HID, HID);

    // per-token head-mix attention -> attn16 [M,1024] (f16)
    attn_kernel<<<M / 8, 128, 0, stream>>>(qkv16, scale, attn16);

    // output GEMM: [M,1024] @ [1024,1024]^T + bo -> out (f32)
    gemm_bt<float><<<dim3(HID / 128, M / 128), 256, 0, stream>>>(
        attn16, wo16, bo, out, M, HID, HID);
}